// Round 9
// baseline (251.786 us; speedup 1.0000x reference)
//
#include <hip/hip_runtime.h>

// DIMKT forward. B=512, S=200, E=128.
// dimkt_prep: 158 blocks x 256 thr; table rows folded through W halves.
//   ws layout (floats): C1=0, SD1/SD6 INTERLEAVED at 131200 (row stride 256:
//   SD1 at +0, SD6 at +128), A4=157312, A5=157568, A6=157824.
// HISTORY: R2/R3 paired-DPP logit merge FAILED — out. R2 pre-scaled f16
//   weights out (rounding compounds through kreg). R6 split-2-deep MFMA
//   chains REGRESSED (latency already hidden; adds cost issue slots).
//   R7 deferred swizzle WIN (168.4->166.5). R8 DPP->post-B1 window + idx pad
//   WIN (166.5->162.5).
// dimkt_scan: 256 blocks x 512 thr, 2 batch rows/block. Grid == 1 block/CU:
//   the only 2 waves/SIMD are SAME-block, barrier-locked -> lockstep phases
//   serialize VALU and MFMA bursts (wall ~ sum, not max).
//   * WAVE-PARITY SKEW (R9): odd waves run {VALU gathers -> MFMA}, even waves
//     run {MFMA -> VALU gathers} between the same barriers (stage 2: {g6+DPP
//     -> MFMA} vs {MFMA -> g6+DPP}). Wave-uniform branch (w&1, scalar);
//     per-lane op order unchanged -> bit-identical numerics. One wave's MFMA
//     burst now overlaps the sibling's VALU block in every region.
//   * in-loop barriers are `s_waitcnt lgkmcnt(0); s_barrier` (NO vmcnt drain —
//     table gathers stay in flight across B1, drained at their pre-B2 use)
//   * SPLIT-GATHER across quad parity: even quads {C1[ic],SD1[isd]}+SD6;
//     odd quads {C1[ict],SD1[ist]} (tgt).
//   * DEFERRED SWIZZLE: tgt = swz16(sumPrev) at stage-1 top; involution,
//     preloop seeds sumPrev = tgt0 -> bit-identical.
//   * DPP logit tree in the post-B1 window; part[] has no mid-loop readers.
//   * idx_lds padded to S+2 (pad rows replicate row S-1) — no per-step clamp.
//   * loop-invariant cin2/cin3 C-in for b2/b3; fused tails
//     (sdf=(2*g2)*sig(2*a3)-g2; knew=pka*(1-g6)+g6*kreg).
//   Tile rows: {0,8}=qq, {1,9}=k (stage1), {0,8}=sdf (stage2). Masked frag
//   reads with persistent zero frags; indices LDS-preloaded.

#define S_ 200
#define E_ 128
#define RS 136   // halves per LDS row

typedef float  float4v __attribute__((ext_vector_type(4)));
typedef _Float16 f16x8 __attribute__((ext_vector_type(8)));

// workgroup barrier with LDS-only drain: leaves vmcnt in flight
#define BAR() asm volatile("s_waitcnt lgkmcnt(0)\n\ts_barrier" ::: "memory")

#define MFMA(A, B, C) __builtin_amdgcn_mfma_f32_16x16x32_f16((A), (B), (C), 0, 0, 0)

__device__ __forceinline__ float fast_sigmoid(float x) {
  return __builtin_amdgcn_rcpf(1.f + __expf(-x));
}
__device__ __forceinline__ float swz16(float x) {
  return __builtin_bit_cast(float,
      __builtin_amdgcn_ds_swizzle(__builtin_bit_cast(int, x), 0x401F));
}

// x + row_shr:<ctrl> shifted x (bound_ctrl: zeros in); sum lands in lane15 of each 16-row
#define DPP_ADD(x, ctrl) \
  ((x) + __builtin_bit_cast(float, __builtin_amdgcn_update_dpp( \
       0, __builtin_bit_cast(int, (x)), (ctrl), 0xf, 0xf, true)))

__device__ __forceinline__ f16x8 cvt8(const float* __restrict__ p) {
  float4v a = *(const float4v*)p;
  float4v b = *(const float4v*)(p + 4);
  f16x8 r;
  r[0] = (_Float16)a[0]; r[1] = (_Float16)a[1];
  r[2] = (_Float16)a[2]; r[3] = (_Float16)a[3];
  r[4] = (_Float16)b[0]; r[5] = (_Float16)b[1];
  r[6] = (_Float16)b[2]; r[7] = (_Float16)b[3];
  return r;
}

// ---------------- prep: 8 rows/block, coalesced LDS-staged W ----------------
__global__ __launch_bounds__(256) void dimkt_prep(
    const float* __restrict__ c_table, const float* __restrict__ sd_table,
    const float* __restrict__ a_table,
    const float* __restrict__ W1, const float* __restrict__ b1,
    const float* __restrict__ W4, const float* __restrict__ b4,
    const float* __restrict__ W5, const float* __restrict__ b5,
    const float* __restrict__ W6, const float* __restrict__ b6,
    float* __restrict__ ws) {
  __shared__ __attribute__((aligned(16))) float s_src[8][E_];
  __shared__ float s_w[E_][33];
  const int blk = blockIdx.x, t = threadIdx.x;
  const int e = t & 127, h = t >> 7;
  const float* src; const float* wb; const float* bias; float* dst;
  int r0, maxrow, wstr, woff, dstr;
  if (blk < 129)      { r0 = blk * 8;       src = c_table;  maxrow = 1024; wb = W1; wstr = 256; woff = 0;   bias = nullptr; dst = ws;          dstr = 128; }
  else if (blk < 142) { r0 = (blk-129) * 8; src = sd_table; maxrow = 101;  wb = W1; wstr = 256; woff = 128; bias = b1;      dst = ws + 131200; dstr = 256; }
  else if (blk < 155) { r0 = (blk-142) * 8; src = sd_table; maxrow = 101;  wb = W6; wstr = 384; woff = 256; bias = nullptr; dst = ws + 131328; dstr = 256; }
  else if (blk == 155){ r0 = 0;             src = a_table;  maxrow = 1;    wb = W4; wstr = 256; woff = 128; bias = b4;      dst = ws + 157312; dstr = 128; }
  else if (blk == 156){ r0 = 0;             src = a_table;  maxrow = 1;    wb = W5; wstr = 256; woff = 128; bias = b5;      dst = ws + 157568; dstr = 128; }
  else                { r0 = 0;             src = a_table;  maxrow = 1;    wb = W6; wstr = 384; woff = 128; bias = b6;      dst = ws + 157824; dstr = 128; }
  #pragma unroll
  for (int i = 0; i < 4; ++i) {
    int idx = i * 256 + t, row = idx >> 7, col = idx & 127;
    int rr = r0 + row; if (rr > maxrow) rr = maxrow;
    s_src[row][col] = src[rr * E_ + col];
  }
  float binit = bias ? bias[e] : 0.f;
  float acc[4] = {binit, binit, binit, binit};
  for (int k0 = 0; k0 < 4; ++k0) {
    __syncthreads();                 // first: s_src ready; later: s_w reuse safe
    #pragma unroll
    for (int i = 0; i < 16; ++i) {
      int idx = i * 256 + t;
      s_w[idx >> 5][idx & 31] = wb[(idx >> 5) * wstr + woff + k0 * 32 + (idx & 31)];
    }
    __syncthreads();
    #pragma unroll 4
    for (int kk = 0; kk < 32; ++kk) {
      float wv = s_w[e][kk];
      #pragma unroll
      for (int g = 0; g < 4; ++g)
        acc[g] += wv * s_src[h * 4 + g][k0 * 32 + kk];
    }
  }
  #pragma unroll
  for (int g = 0; g < 4; ++g) {
    int row = r0 + h * 4 + g;
    if (row <= maxrow) dst[row * dstr + e] = acc[g];
  }
}

// ---------------- the scan ----------------
__global__ __launch_bounds__(512, 2) void dimkt_scan(
    const int* __restrict__ c, const int* __restrict__ sd, const int* __restrict__ a,
    const int* __restrict__ cshft, const int* __restrict__ sdshft,
    const float* __restrict__ knowledge,
    const float* __restrict__ W2, const float* __restrict__ b2,
    const float* __restrict__ W3, const float* __restrict__ b3,
    const float* __restrict__ W4, const float* __restrict__ W5,
    const float* __restrict__ W6,
    const float* __restrict__ ws, float* __restrict__ out) {

  const float* __restrict__ C1   = ws;
  const float* __restrict__ SD1I = ws + 131200;   // stride 256; +128 = SD6
  const float* __restrict__ A4  = ws + 157312;
  const float* __restrict__ A5  = ws + 157568;
  const float* __restrict__ A6  = ws + 157824;

  const int tid  = threadIdx.x;
  const int w    = tid >> 6;        // wave 0..7 -> E-slice [16w, 16w+16)
  const int lane = tid & 63;
  const int l15  = lane & 15;
  const int q    = lane >> 4;       // quad 0..3
  const int qodd = q & 1;
  const int e    = w * 16 + l15;    // output column this lane owns
  const int j    = q >> 1;          // batch row within block
  const int bj   = blockIdx.x * 2 + j;
  const bool wodd = (w & 1) != 0;   // wave-parity for the schedule skew

  __shared__ __attribute__((aligned(16))) _Float16 A1[16 * RS];
  __shared__ __attribute__((aligned(16))) _Float16 A2[16 * RS];
  __shared__ __attribute__((aligned(32))) int idx_lds[S_ + 2][2][8];
  __shared__ float part[8][2][S_];

  // one-time coalesced index preload (padded 2 past the end: pad rows
  // replicate row S_-1, so the unclamped s+2 read yields identical values)
  for (int i = tid; i < 2 * (S_ + 2); i += 512) {
    const int jj = (i >= S_ + 2) ? 1 : 0;
    const int ss = jj ? (i - (S_ + 2)) : i;
    const int sc = ss < S_ ? ss : S_ - 1;
    const int src = (blockIdx.x * 2 + jj) * S_ + sc;
    idx_lds[ss][jj][0] = c[src];
    idx_lds[ss][jj][1] = sd[src];
    idx_lds[ss][jj][2] = a[src];
    idx_lds[ss][jj][3] = cshft[src];
    idx_lds[ss][jj][4] = sdshft[src];
  }

  // tile rows: qq/sdf -> j*8 (0,8); k -> j*8+1 (1,9). Stores by even quads only.
  const int stq = (j * 8) * RS + e;
  const int stk = stq + RS;
  const int rd0 = l15 * RS + q * 8;   // A-frag read base (halves), +32*t per frag
  const bool m1 = (l15 & 6) == 0;     // rows {0,1,8,9} (stage 1)
  const bool m2 = (l15 & 7) == 0;     // rows {0,8}     (stage 2)

  // Weight B-fragments: lane holds W[e][32t + 8q + 0..7]  (RAW — no pre-scale)
  f16x8 w2f[4], w3f[4], w4f[4], w5f[4], w6f[4];
  #pragma unroll
  for (int t = 0; t < 4; ++t) {
    const int ko = t * 32 + q * 8;
    w2f[t] = cvt8(W2 + e * 128 + ko);
    w3f[t] = cvt8(W3 + e * 128 + ko);
    w4f[t] = cvt8(W4 + e * 256 + ko);   // first E cols
    w5f[t] = cvt8(W5 + e * 256 + ko);
    w6f[t] = cvt8(W6 + e * 384 + ko);   // k third of W6
  }
  const float b2e = b2[e], b3e = b3[e];
  const float A4t0 = A4[e], A4t1 = A4[E_ + e];
  const float A5t0 = A5[e], A5t1 = A5[E_ + e];
  const float A6t0 = A6[e], A6t1 = A6[E_ + e];

  float kreg = knowledge[e];

  // pre-loop gathers (outside steady loop; full form, once)
  const int base = bj * S_;
  int ic = c[base], isd = sd[base], ia = a[base], ict = cshft[base], ist = sdshft[base];
  float inT0 = C1[ic * E_ + e] + SD1I[isd * 256 + e];
  float sd6v = SD1I[isd * 256 + 128 + e];
  float a4v = ia ? A4t1 : A4t0;
  float a5v = ia ? A5t1 : A5t0;
  float a6v = ia ? A6t1 : A6t0;
  float tgt  = C1[ict * E_ + e] + SD1I[ist * 256 + e];
  // seed for deferred swizzle: all lanes hold the same per-(j,e) tgt0 here,
  // so tgt = swz16(sumPrev) at s=0 reproduces tgt0 exactly.
  float sumPrev = tgt;
  int nic = c[base + 1], nisd = sd[base + 1], nia = a[base + 1],
      nict = cshft[base + 1], nist = sdshft[base + 1];

  __syncthreads();                         // idx preload visible
  if (!qodd) {
    A1[stq] = (_Float16)(kreg - inT0);     // qq row
    A1[stk] = (_Float16)kreg;              // k row
  }
  __syncthreads();                         // initial A1 staged

  // persistent zero frags: masked-out lanes never write them -> stay 0
  f16x8 f0{}, f1{}, f2{}, f3{};
  f16x8 g0{}, g1{}, g2v{}, g3{};

  // loop-invariant C-in for the b2/b3 bias chains (no per-step movs);
  // persistent accumulators for the per-step-bias chains (stale regs benign).
  const float4v cin2{b2e, 0.f, 0.f, 0.f};
  const float4v cin3{b3e, 0.f, 0.f, 0.f};
  float4v acc6{0.f,0.f,0.f,0.f};
  float4v acc4{0.f,0.f,0.f,0.f}, acc5{0.f,0.f,0.f,0.f};

  float pprev = 0.f;                       // previous step's logit product
  int   sprev = 0;

// ---- schedule segments (same ops, two orders; per-lane order unchanged) ----
#define S1_GATHER {                                                           \
    const int selc  = qodd ? nict : nic;                                      \
    const int selsd = qodd ? nist : nisd;                                     \
    L1 = C1[selc * E_ + e];                                                   \
    const float* pSD = SD1I + selsd * 256 + e;                                \
    L2   = pSD[0];                                                            \
    nsd6 = pSD[128];                                                          \
    na4 = nia ? A4t1 : A4t0;                                                  \
    na5 = nia ? A5t1 : A5t0;                                                  \
    na6 = nia ? A6t1 : A6t0;                                                  \
    iv = *(const int4*)&idx_lds[s + 2][j][0];                                 \
    tist = idx_lds[s + 2][j][4]; }

#define S1_MFMA {                                                             \
    a2 = MFMA(f0, w2f[0], cin2);                                              \
    a3 = MFMA(f0, w3f[0], cin3);                                              \
    a2 = MFMA(f1, w2f[1], a2);                                                \
    a3 = MFMA(f1, w3f[1], a3);                                                \
    a2 = MFMA(f2, w2f[2], a2);                                                \
    a3 = MFMA(f2, w3f[2], a3);                                                \
    a2 = MFMA(f3, w2f[3], a2);                                                \
    a3 = MFMA(f3, w3f[3], a3);                                                \
    acc6[1] = a6v + sd6v;                 /* k rows 1,9 -> D reg1 */          \
    acc6 = MFMA(f0, w6f[0], acc6);                                            \
    acc6 = MFMA(f1, w6f[1], acc6); }

#define S1_TAIL {                                                             \
    const float g2  = fast_sigmoid(a2[0]);                                    \
    const float G2  = g2 + g2;                                                \
    const float sg3 = __builtin_amdgcn_rcpf(1.f + __expf(-2.f * a3[0]));      \
    const float sdfv = G2 * sg3 - g2;                                         \
    if (!qodd) A2[stq] = (_Float16)sdfv;                                      \
    acc6 = MFMA(f2, w6f[2], acc6);                                            \
    acc6 = MFMA(f3, w6f[3], acc6); }

#define S2_PRE {                                                              \
    g6v = fast_sigmoid(acc6[1]);                                              \
    gkv = g6v * kreg;                                                         \
    h6v = 1.f - g6v;                                                          \
    if (s > 0) {                                                              \
      float pr = pprev;                                                       \
      pr = DPP_ADD(pr, 0x111);                                                \
      pr = DPP_ADD(pr, 0x112);                                                \
      pr = DPP_ADD(pr, 0x114);                                                \
      pr = DPP_ADD(pr, 0x118);                                                \
      if (l15 == 15 && !qodd) part[w][j][sprev] = pr;                         \
    } }

#define S2_MFMA {                                                             \
    acc4[0] = a4v;                                                            \
    acc4 = MFMA(g0, w4f[0], acc4);                                            \
    acc4 = MFMA(g1, w4f[1], acc4);                                            \
    acc4 = MFMA(g2v, w4f[2], acc4);                                           \
    acc4 = MFMA(g3, w4f[3], acc4);                                            \
    acc5[0] = a5v;                                                            \
    acc5 = MFMA(g0, w5f[0], acc5);                                            \
    acc5 = MFMA(g1, w5f[1], acc5);                                            \
    s4v  = fast_sigmoid(acc4[0]);                                             \
    S42v = s4v + s4v;                                                         \
    acc5 = MFMA(g2v, w5f[2], acc5);                                           \
    acc5 = MFMA(g3, w5f[3], acc5); }

  #pragma unroll 2
  for (int s = 0; s < S_; ++s) {
    float4v a2, a3;
    float L1, L2, nsd6, na4, na5, na6;
    int4 iv; int tist;
    float g6v, gkv, h6v, s4v, S42v;

    // ---- stage 1 ----
    if (m1) {
      f0 = *(const f16x8*)&A1[rd0];
      f1 = *(const f16x8*)&A1[rd0 + 32];
      f2 = *(const f16x8*)&A1[rd0 + 64];
      f3 = *(const f16x8*)&A1[rd0 + 96];
    }
    // deferred quad-parity swap: this step's tgt from last step's gather sums
    tgt = swz16(sumPrev);

    if (wodd) { S1_GATHER; S1_MFMA; S1_TAIL; }   // VALU first (fills read wait)
    else      { S1_MFMA; S1_GATHER; S1_TAIL; }   // MFMA first (anti-phase)

    BAR();                                     // B1: sdf staged (lgkm only)

    // ---- stage 2 ----
    if (m2) {
      g0  = *(const f16x8*)&A2[rd0];
      g1  = *(const f16x8*)&A2[rd0 + 32];
      g2v = *(const f16x8*)&A2[rd0 + 64];
      g3  = *(const f16x8*)&A2[rd0 + 96];
    }

    if (wodd) { S2_PRE; S2_MFMA; }               // VALU first
    else      { S2_MFMA; S2_PRE; }               // MFMA first

    // pka = s4*tanh(a5) = S42*sig(2*a5) - s4; knew = pka*(1-g6) + g6*k
    const float sg5 = __builtin_amdgcn_rcpf(1.f + __expf(-2.f * acc5[0]));
    const float pka = S42v * sg5 - s4v;        // real in even quads
    const float knew = pka * h6v + gkv;
    kreg = knew;

    // even quads' sum = inT(s+1); odd quads' = tgt(s+1). The parity swap is
    // DEFERRED to next step's stage-1 (swz16 off B2's lgkm drain path).
    const float sum = L1 + L2;                 // vmcnt wait lands here

    if (!qodd) {
      A1[stq] = (_Float16)(knew - sum);        // next qq
      A1[stk] = (_Float16)knew;                // next k
    }

    pprev = tgt * knew;                        // logit product; reduced next step
    sprev = s;

    sumPrev = sum;
    sd6v = nsd6; a4v = na4; a5v = na5; a6v = na6;
    nic = iv.x; nisd = iv.y; nia = iv.z; nict = iv.w; nist = tist;

    BAR();                                     // B2: A1' staged (lgkm only)
  }

  // last step's logit partial
  {
    float pr = pprev;
    pr = DPP_ADD(pr, 0x111);
    pr = DPP_ADD(pr, 0x112);
    pr = DPP_ADD(pr, 0x114);
    pr = DPP_ADD(pr, 0x118);
    if (l15 == 15 && !qodd) part[w][j][sprev] = pr;
  }

  // final cross-wave reduce + sigmoid + store
  __syncthreads();
  for (int i = tid; i < 2 * S_; i += 512) {
    const int jj = (i >= S_) ? 1 : 0;
    const int ss = jj ? (i - S_) : i;
    float logit = 0.f;
    #pragma unroll
    for (int x = 0; x < 8; ++x) logit += part[x][jj][ss];
    out[(blockIdx.x * 2 + jj) * S_ + ss] = fast_sigmoid(logit);
  }
}

extern "C" void kernel_launch(void* const* d_in, const int* in_sizes, int n_in,
                              void* d_out, int out_size, void* d_ws, size_t ws_size,
                              hipStream_t stream) {
  const int*   c         = (const int*)  d_in[0];
  const int*   sd        = (const int*)  d_in[1];
  const int*   a         = (const int*)  d_in[2];
  const int*   cshft     = (const int*)  d_in[3];
  const int*   sdshft    = (const int*)  d_in[4];
  const float* c_table   = (const float*)d_in[5];
  const float* sd_table  = (const float*)d_in[6];
  const float* a_table   = (const float*)d_in[7];
  const float* knowledge = (const float*)d_in[8];
  const float* W1 = (const float*)d_in[9];  const float* b1 = (const float*)d_in[10];
  const float* W2 = (const float*)d_in[11]; const float* b2 = (const float*)d_in[12];
  const float* W3 = (const float*)d_in[13]; const float* b3 = (const float*)d_in[14];
  const float* W4 = (const float*)d_in[15]; const float* b4 = (const float*)d_in[16];
  const float* W5 = (const float*)d_in[17]; const float* b5 = (const float*)d_in[18];
  const float* W6 = (const float*)d_in[19]; const float* b6 = (const float*)d_in[20];
  float* ws  = (float*)d_ws;
  float* out = (float*)d_out;
  (void)in_sizes; (void)n_in; (void)out_size; (void)ws_size;

  dimkt_prep<<<158, 256, 0, stream>>>(c_table, sd_table, a_table,
                                      W1, b1, W4, b4, W5, b5, W6, b6, ws);
  dimkt_scan<<<256, 512, 0, stream>>>(c, sd, a, cshft, sdshft, knowledge,
                                      W2, b2, W3, b3, W4, W5, W6, ws, out);
}

// Round 11
// 246.080 us; speedup vs baseline: 1.0232x; 1.0232x over previous
//
#include <hip/hip_runtime.h>

// DIMKT forward. B=512, S=200, E=128.
// dimkt_prep: 158 blocks x 256 thr; table rows folded through W halves.
//   ws layout (floats): C1=0, SD1/SD6 INTERLEAVED at 131200 (row stride 256:
//   SD1 at +0, SD6 at +128), A4=157312, A5=157568, A6=157824.
// HISTORY: R2/R3 paired-DPP logit merge FAILED — out. R2 pre-scaled f16
//   weights out (rounding compounds through kreg). R6 split-2-deep MFMA
//   chains REGRESSED (latency already hidden; adds cost issue slots).
//   R7 deferred swizzle WIN (168.4->166.5). R8 DPP->post-B1 window + idx pad
//   WIN (166.5->162.5). R9 wave-parity anti-phase skew REGRESSED
//   (162.5->171.7: body duplication defeated compiler scheduling) — reverted.
//   R10 = R8 + s_setprio(1) around MFMA clusters (T5; numerics-invariant).
//   R10 submission hit an infra failure (container died twice) — this is the
//   identical kernel resubmitted to collect its measurement.
// dimkt_scan: 256 blocks x 512 thr, 2 batch rows/block (r6 decomposition —
//   measured-best; step-wall is per-SIMD-issue-bound + barrier-drain):
//   * in-loop barriers are `s_waitcnt lgkmcnt(0); s_barrier` (NO vmcnt drain —
//     table gathers stay in flight across B1, drained at their pre-B2 use)
//   * SPLIT-GATHER across quad parity: even quads gather {C1[ic],SD1[isd]}
//     (inT) + SD6 via +128 offset; odd quads gather {C1[ict],SD1[ist]} (tgt).
//   * DEFERRED SWIZZLE: tgt = swz16(sumPrev) at stage-1 top (hidden under
//     frag ds_reads) — keeps the swizzle's LDS latency off B2's lgkm drain.
//     Bit-identical: swz16 is an involution; preloop seeds sumPrev = tgt0.
//   * DPP LOGIT AT STAGE-2 TOP: the 4-step DPP tree + part[] write sits
//     after B1, between the g-frag ds_read issue and the acc4 MFMA chain —
//     fills the post-B1 lgkm-wait hole (stage-1 top was over-subscribed).
//   * idx_lds padded to S+2 (pad rows replicate row S-1) — no per-step clamp.
//   * loop-invariant cin2/cin3 C-in for b2/b3 (no per-step bias movs).
//   * tails fused: sdf = (2*g2)*sig(2*a3)-g2; knew = pka*(1-g6) + g6*kreg
//     with products precomputed in the MFMA shadow.
//   * MFMA chains ordered a2,a3 first so transcendentals + sdf store overlap
//     acc6 MFMA issue; g6 sigmoid after B1 (overlaps g-frag ds_read).
//   Tile rows: {0,8}=qq, {1,9}=k (stage1: W2,W3 -> D reg0; W6 -> D reg1; all
//   real values in quads 0/2), {0,8}=sdf (stage2). Masked frag reads with
//   persistent zero frags; indices LDS-preloaded.

#define S_ 200
#define E_ 128
#define RS 136   // halves per LDS row

typedef float  float4v __attribute__((ext_vector_type(4)));
typedef _Float16 f16x8 __attribute__((ext_vector_type(8)));

// workgroup barrier with LDS-only drain: leaves vmcnt in flight
#define BAR() asm volatile("s_waitcnt lgkmcnt(0)\n\ts_barrier" ::: "memory")

#define MFMA(A, B, C) __builtin_amdgcn_mfma_f32_16x16x32_f16((A), (B), (C), 0, 0, 0)

__device__ __forceinline__ float fast_sigmoid(float x) {
  return __builtin_amdgcn_rcpf(1.f + __expf(-x));
}
__device__ __forceinline__ float swz16(float x) {
  return __builtin_bit_cast(float,
      __builtin_amdgcn_ds_swizzle(__builtin_bit_cast(int, x), 0x401F));
}

// x + row_shr:<ctrl> shifted x (bound_ctrl: zeros in); sum lands in lane15 of each 16-row
#define DPP_ADD(x, ctrl) \
  ((x) + __builtin_bit_cast(float, __builtin_amdgcn_update_dpp( \
       0, __builtin_bit_cast(int, (x)), (ctrl), 0xf, 0xf, true)))

__device__ __forceinline__ f16x8 cvt8(const float* __restrict__ p) {
  float4v a = *(const float4v*)p;
  float4v b = *(const float4v*)(p + 4);
  f16x8 r;
  r[0] = (_Float16)a[0]; r[1] = (_Float16)a[1];
  r[2] = (_Float16)a[2]; r[3] = (_Float16)a[3];
  r[4] = (_Float16)b[0]; r[5] = (_Float16)b[1];
  r[6] = (_Float16)b[2]; r[7] = (_Float16)b[3];
  return r;
}

// ---------------- prep: 8 rows/block, coalesced LDS-staged W ----------------
__global__ __launch_bounds__(256) void dimkt_prep(
    const float* __restrict__ c_table, const float* __restrict__ sd_table,
    const float* __restrict__ a_table,
    const float* __restrict__ W1, const float* __restrict__ b1,
    const float* __restrict__ W4, const float* __restrict__ b4,
    const float* __restrict__ W5, const float* __restrict__ b5,
    const float* __restrict__ W6, const float* __restrict__ b6,
    float* __restrict__ ws) {
  __shared__ __attribute__((aligned(16))) float s_src[8][E_];
  __shared__ float s_w[E_][33];
  const int blk = blockIdx.x, t = threadIdx.x;
  const int e = t & 127, h = t >> 7;
  const float* src; const float* wb; const float* bias; float* dst;
  int r0, maxrow, wstr, woff, dstr;
  if (blk < 129)      { r0 = blk * 8;       src = c_table;  maxrow = 1024; wb = W1; wstr = 256; woff = 0;   bias = nullptr; dst = ws;          dstr = 128; }
  else if (blk < 142) { r0 = (blk-129) * 8; src = sd_table; maxrow = 101;  wb = W1; wstr = 256; woff = 128; bias = b1;      dst = ws + 131200; dstr = 256; }
  else if (blk < 155) { r0 = (blk-142) * 8; src = sd_table; maxrow = 101;  wb = W6; wstr = 384; woff = 256; bias = nullptr; dst = ws + 131328; dstr = 256; }
  else if (blk == 155){ r0 = 0;             src = a_table;  maxrow = 1;    wb = W4; wstr = 256; woff = 128; bias = b4;      dst = ws + 157312; dstr = 128; }
  else if (blk == 156){ r0 = 0;             src = a_table;  maxrow = 1;    wb = W5; wstr = 256; woff = 128; bias = b5;      dst = ws + 157568; dstr = 128; }
  else                { r0 = 0;             src = a_table;  maxrow = 1;    wb = W6; wstr = 384; woff = 128; bias = b6;      dst = ws + 157824; dstr = 128; }
  #pragma unroll
  for (int i = 0; i < 4; ++i) {
    int idx = i * 256 + t, row = idx >> 7, col = idx & 127;
    int rr = r0 + row; if (rr > maxrow) rr = maxrow;
    s_src[row][col] = src[rr * E_ + col];
  }
  float binit = bias ? bias[e] : 0.f;
  float acc[4] = {binit, binit, binit, binit};
  for (int k0 = 0; k0 < 4; ++k0) {
    __syncthreads();                 // first: s_src ready; later: s_w reuse safe
    #pragma unroll
    for (int i = 0; i < 16; ++i) {
      int idx = i * 256 + t;
      s_w[idx >> 5][idx & 31] = wb[(idx >> 5) * wstr + woff + k0 * 32 + (idx & 31)];
    }
    __syncthreads();
    #pragma unroll 4
    for (int kk = 0; kk < 32; ++kk) {
      float wv = s_w[e][kk];
      #pragma unroll
      for (int g = 0; g < 4; ++g)
        acc[g] += wv * s_src[h * 4 + g][k0 * 32 + kk];
    }
  }
  #pragma unroll
  for (int g = 0; g < 4; ++g) {
    int row = r0 + h * 4 + g;
    if (row <= maxrow) dst[row * dstr + e] = acc[g];
  }
}

// ---------------- the scan ----------------
__global__ __launch_bounds__(512, 2) void dimkt_scan(
    const int* __restrict__ c, const int* __restrict__ sd, const int* __restrict__ a,
    const int* __restrict__ cshft, const int* __restrict__ sdshft,
    const float* __restrict__ knowledge,
    const float* __restrict__ W2, const float* __restrict__ b2,
    const float* __restrict__ W3, const float* __restrict__ b3,
    const float* __restrict__ W4, const float* __restrict__ W5,
    const float* __restrict__ W6,
    const float* __restrict__ ws, float* __restrict__ out) {

  const float* __restrict__ C1   = ws;
  const float* __restrict__ SD1I = ws + 131200;   // stride 256; +128 = SD6
  const float* __restrict__ A4  = ws + 157312;
  const float* __restrict__ A5  = ws + 157568;
  const float* __restrict__ A6  = ws + 157824;

  const int tid  = threadIdx.x;
  const int w    = tid >> 6;        // wave 0..7 -> E-slice [16w, 16w+16)
  const int lane = tid & 63;
  const int l15  = lane & 15;
  const int q    = lane >> 4;       // quad 0..3
  const int qodd = q & 1;
  const int e    = w * 16 + l15;    // output column this lane owns
  const int j    = q >> 1;          // batch row within block
  const int bj   = blockIdx.x * 2 + j;

  __shared__ __attribute__((aligned(16))) _Float16 A1[16 * RS];
  __shared__ __attribute__((aligned(16))) _Float16 A2[16 * RS];
  __shared__ __attribute__((aligned(32))) int idx_lds[S_ + 2][2][8];
  __shared__ float part[8][2][S_];

  // one-time coalesced index preload (padded 2 past the end: pad rows
  // replicate row S_-1, so the unclamped s+2 read yields identical values)
  for (int i = tid; i < 2 * (S_ + 2); i += 512) {
    const int jj = (i >= S_ + 2) ? 1 : 0;
    const int ss = jj ? (i - (S_ + 2)) : i;
    const int sc = ss < S_ ? ss : S_ - 1;
    const int src = (blockIdx.x * 2 + jj) * S_ + sc;
    idx_lds[ss][jj][0] = c[src];
    idx_lds[ss][jj][1] = sd[src];
    idx_lds[ss][jj][2] = a[src];
    idx_lds[ss][jj][3] = cshft[src];
    idx_lds[ss][jj][4] = sdshft[src];
  }

  // tile rows: qq/sdf -> j*8 (0,8); k -> j*8+1 (1,9). Stores by even quads only.
  const int stq = (j * 8) * RS + e;
  const int stk = stq + RS;
  const int rd0 = l15 * RS + q * 8;   // A-frag read base (halves), +32*t per frag
  const bool m1 = (l15 & 6) == 0;     // rows {0,1,8,9} (stage 1)
  const bool m2 = (l15 & 7) == 0;     // rows {0,8}     (stage 2)

  // Weight B-fragments: lane holds W[e][32t + 8q + 0..7]  (RAW — no pre-scale)
  f16x8 w2f[4], w3f[4], w4f[4], w5f[4], w6f[4];
  #pragma unroll
  for (int t = 0; t < 4; ++t) {
    const int ko = t * 32 + q * 8;
    w2f[t] = cvt8(W2 + e * 128 + ko);
    w3f[t] = cvt8(W3 + e * 128 + ko);
    w4f[t] = cvt8(W4 + e * 256 + ko);   // first E cols
    w5f[t] = cvt8(W5 + e * 256 + ko);
    w6f[t] = cvt8(W6 + e * 384 + ko);   // k third of W6
  }
  const float b2e = b2[e], b3e = b3[e];
  const float A4t0 = A4[e], A4t1 = A4[E_ + e];
  const float A5t0 = A5[e], A5t1 = A5[E_ + e];
  const float A6t0 = A6[e], A6t1 = A6[E_ + e];

  float kreg = knowledge[e];

  // pre-loop gathers (outside steady loop; full form, once)
  const int base = bj * S_;
  int ic = c[base], isd = sd[base], ia = a[base], ict = cshft[base], ist = sdshft[base];
  float inT0 = C1[ic * E_ + e] + SD1I[isd * 256 + e];
  float sd6v = SD1I[isd * 256 + 128 + e];
  float a4v = ia ? A4t1 : A4t0;
  float a5v = ia ? A5t1 : A5t0;
  float a6v = ia ? A6t1 : A6t0;
  float tgt  = C1[ict * E_ + e] + SD1I[ist * 256 + e];
  // seed for deferred swizzle: all lanes hold the same per-(j,e) tgt0 here,
  // so tgt = swz16(sumPrev) at s=0 reproduces tgt0 exactly.
  float sumPrev = tgt;
  int nic = c[base + 1], nisd = sd[base + 1], nia = a[base + 1],
      nict = cshft[base + 1], nist = sdshft[base + 1];

  __syncthreads();                         // idx preload visible
  if (!qodd) {
    A1[stq] = (_Float16)(kreg - inT0);     // qq row
    A1[stk] = (_Float16)kreg;              // k row
  }
  __syncthreads();                         // initial A1 staged

  // persistent zero frags: masked-out lanes never write them -> stay 0
  f16x8 f0{}, f1{}, f2{}, f3{};
  f16x8 g0{}, g1{}, g2v{}, g3{};

  // loop-invariant C-in for the b2/b3 bias chains (no per-step movs);
  // persistent accumulators for the per-step-bias chains (stale regs benign).
  const float4v cin2{b2e, 0.f, 0.f, 0.f};
  const float4v cin3{b3e, 0.f, 0.f, 0.f};
  float4v acc6{0.f,0.f,0.f,0.f};
  float4v acc4{0.f,0.f,0.f,0.f}, acc5{0.f,0.f,0.f,0.f};

  float pprev = 0.f;                       // previous step's logit product
  int   sprev = 0;

  #pragma unroll 2
  for (int s = 0; s < S_; ++s) {
    // ---- stage 1: frags feed W2,W3 (qq rows 0,8) and W6 (k rows 1,9) ----
    if (m1) {
      f0 = *(const f16x8*)&A1[rd0];
      f1 = *(const f16x8*)&A1[rd0 + 32];
      f2 = *(const f16x8*)&A1[rd0 + 64];
      f3 = *(const f16x8*)&A1[rd0 + 96];
    }

    // deferred quad-parity swap: this step's tgt from last step's gather sums.
    // Issued here (overlaps frag ds_reads); consumed at pprev, end of stage 2.
    tgt = swz16(sumPrev);

    // next step's table gathers, split across quad parity (all lanes hold all
    // indices): even quads gather the inT pair + SD6 (via +128 imm off the
    // SD1 address); odd quads gather the tgt pair. In flight across B1,
    // consumed just before the A1 write at end of stage 2.
    const int selc  = qodd ? nict : nic;
    const int selsd = qodd ? nist : nisd;
    const float L1 = C1[selc * E_ + e];
    const float* pSD = SD1I + selsd * 256 + e;
    const float L2   = pSD[0];
    const float nsd6 = pSD[128];      // SD6[nisd] in even quads (used);
    const float na4 = nia ? A4t1 : A4t0;    // garbage in odd (dead rows)
    const float na5 = nia ? A5t1 : A5t0;
    const float na6 = nia ? A6t1 : A6t0;

    // s+2 indices from LDS (lgkm; broadcast; padded -> no clamp)
    const int4 iv = *(const int4*)&idx_lds[s + 2][j][0];
    const int tist = idx_lds[s + 2][j][4];

    // a2 and a3 chains first -> their transcendentals + sdf store overlap
    // the acc6 MFMA issue (separate MFMA/VALU pipes). 4-deep chains (R6's
    // 2-deep split regressed: latency already hidden, adds cost issue).
    // setprio(1) biases the 2-wave issue arbiter toward the MFMA-feeding
    // wave through this cluster (T5; values unaffected).
    __builtin_amdgcn_s_setprio(1);
    float4v a2 = MFMA(f0, w2f[0], cin2);
    float4v a3 = MFMA(f0, w3f[0], cin3);
    a2 = MFMA(f1, w2f[1], a2);
    a3 = MFMA(f1, w3f[1], a3);
    a2 = MFMA(f2, w2f[2], a2);
    a3 = MFMA(f2, w3f[2], a3);
    a2 = MFMA(f3, w2f[3], a2);
    a3 = MFMA(f3, w3f[3], a3);

    acc6[1] = a6v + sd6v;                 // k rows 1,9 -> D reg1
    acc6 = MFMA(f0, w6f[0], acc6);
    acc6 = MFMA(f1, w6f[1], acc6);

    // sdf = sig(a2)*tanh(a3) = (2*g2)*sig(2*a3) - g2
    const float g2  = fast_sigmoid(a2[0]);     // overlaps acc6 MFMA issue
    const float G2  = g2 + g2;
    const float sg3 = __builtin_amdgcn_rcpf(1.f + __expf(-2.f * a3[0]));
    const float sdfv = G2 * sg3 - g2;
    if (!qodd) A2[stq] = (_Float16)sdfv;

    acc6 = MFMA(f2, w6f[2], acc6);
    acc6 = MFMA(f3, w6f[3], acc6);
    __builtin_amdgcn_s_setprio(0);

    BAR();                                     // B1: sdf staged (lgkm only)

    // ---- stage 2: W4, W5 on sdf (rows 0,8 only) ----
    if (m2) {
      g0  = *(const f16x8*)&A2[rd0];
      g1  = *(const f16x8*)&A2[rd0 + 32];
      g2v = *(const f16x8*)&A2[rd0 + 64];
      g3  = *(const f16x8*)&A2[rd0 + 96];
    }

    const float g6 = fast_sigmoid(acc6[1]);    // overlaps g-frag ds_read
    const float gk = g6 * kreg;
    const float h6 = 1.f - g6;

    // previous step's logit reduction — placed HERE (post-B1 window): fills
    // the g-frag lgkm wait alongside g6. part[] has no mid-loop readers.
    if (s > 0) {
      float pr = pprev;
      pr = DPP_ADD(pr, 0x111);
      pr = DPP_ADD(pr, 0x112);
      pr = DPP_ADD(pr, 0x114);
      pr = DPP_ADD(pr, 0x118);
      if (l15 == 15 && !qodd) part[w][j][sprev] = pr;
    }

    __builtin_amdgcn_s_setprio(1);
    acc4[0] = a4v;
    acc4 = MFMA(g0, w4f[0], acc4);
    acc4 = MFMA(g1, w4f[1], acc4);
    acc4 = MFMA(g2v, w4f[2], acc4);
    acc4 = MFMA(g3, w4f[3], acc4);
    acc5[0] = a5v;
    acc5 = MFMA(g0, w5f[0], acc5);
    acc5 = MFMA(g1, w5f[1], acc5);

    const float s4  = fast_sigmoid(acc4[0]);   // overlaps acc5 MFMA issue
    const float S42 = s4 + s4;

    acc5 = MFMA(g2v, w5f[2], acc5);
    acc5 = MFMA(g3, w5f[3], acc5);
    __builtin_amdgcn_s_setprio(0);

    // pka = s4*tanh(a5) = S42*sig(2*a5) - s4; knew = pka*(1-g6) + g6*k
    const float sg5 = __builtin_amdgcn_rcpf(1.f + __expf(-2.f * acc5[0]));
    const float pka = S42 * sg5 - s4;          // real in even quads
    const float knew = pka * h6 + gk;
    kreg = knew;

    // even quads' sum = inT(s+1); odd quads' = tgt(s+1). The parity swap is
    // DEFERRED to next step's stage-1 (swz16 off B2's lgkm drain path).
    const float sum = L1 + L2;                 // vmcnt wait lands here

    if (!qodd) {
      A1[stq] = (_Float16)(knew - sum);        // next qq
      A1[stk] = (_Float16)knew;                // next k
    }

    pprev = tgt * knew;                        // logit product; reduced next step
    sprev = s;

    sumPrev = sum;
    sd6v = nsd6; a4v = na4; a5v = na5; a6v = na6;
    nic = iv.x; nisd = iv.y; nia = iv.z; nict = iv.w; nist = tist;

    BAR();                                     // B2: A1' staged (lgkm only)
  }

  // last step's logit partial
  {
    float pr = pprev;
    pr = DPP_ADD(pr, 0x111);
    pr = DPP_ADD(pr, 0x112);
    pr = DPP_ADD(pr, 0x114);
    pr = DPP_ADD(pr, 0x118);
    if (l15 == 15 && !qodd) part[w][j][sprev] = pr;
  }

  // final cross-wave reduce + sigmoid + store
  __syncthreads();
  for (int i = tid; i < 2 * S_; i += 512) {
    const int jj = (i >= S_) ? 1 : 0;
    const int ss = jj ? (i - S_) : i;
    float logit = 0.f;
    #pragma unroll
    for (int x = 0; x < 8; ++x) logit += part[x][jj][ss];
    out[(blockIdx.x * 2 + jj) * S_ + ss] = fast_sigmoid(logit);
  }
}

extern "C" void kernel_launch(void* const* d_in, const int* in_sizes, int n_in,
                              void* d_out, int out_size, void* d_ws, size_t ws_size,
                              hipStream_t stream) {
  const int*   c         = (const int*)  d_in[0];
  const int*   sd        = (const int*)  d_in[1];
  const int*   a         = (const int*)  d_in[2];
  const int*   cshft     = (const int*)  d_in[3];
  const int*   sdshft    = (const int*)  d_in[4];
  const float* c_table   = (const float*)d_in[5];
  const float* sd_table  = (const float*)d_in[6];
  const float* a_table   = (const float*)d_in[7];
  const float* knowledge = (const float*)d_in[8];
  const float* W1 = (const float*)d_in[9];  const float* b1 = (const float*)d_in[10];
  const float* W2 = (const float*)d_in[11]; const float* b2 = (const float*)d_in[12];
  const float* W3 = (const float*)d_in[13]; const float* b3 = (const float*)d_in[14];
  const float* W4 = (const float*)d_in[15]; const float* b4 = (const float*)d_in[16];
  const float* W5 = (const float*)d_in[17]; const float* b5 = (const float*)d_in[18];
  const float* W6 = (const float*)d_in[19]; const float* b6 = (const float*)d_in[20];
  float* ws  = (float*)d_ws;
  float* out = (float*)d_out;
  (void)in_sizes; (void)n_in; (void)out_size; (void)ws_size;

  dimkt_prep<<<158, 256, 0, stream>>>(c_table, sd_table, a_table,
                                      W1, b1, W4, b4, W5, b5, W6, b6, ws);
  dimkt_scan<<<256, 512, 0, stream>>>(c, sd, a, cshft, sdshft, knowledge,
                                      W2, b2, W3, b3, W4, W5, W6, ws, out);
}